// Round 19
// baseline (233.222 us; speedup 1.0000x reference)
//
#include <hip/hip_runtime.h>
#include <hip/hip_bf16.h>
#include <math.h>

// SharedLora on MI355X — round 19: wave-autonomous blocks, zero barriers.
// Invariant across 5 structures (184-196us): 256-thr blocks + barriers +
// 5 blocks/CU = phase convoy (~30us residence vs ~3us critical path); dur
// insensitive to HBM vs L3 source -> latency-bound, not BW-bound.
// r19: block = 1 wave = one 64-bin tile (8000/64 = 125 exact). Wave stages
// U[20][64] in 6.6KB LDS (wave-synchronous, no __syncthreads), computes KL
// quads in-register (L6 from staging regs; L5/L4/L3 one column-unit per
// lane), then 5x4-cluster w-projection with compT via uniform s_loads.
// 24 independent waves/CU, no inter-wave coupling. No MFMA (proven no-op
// here). launch_bounds(64,6) caps VGPR 85 vs ~50 live. No global atomics.

#define NROI 256
#define NC 20
#define NFINAL 8000
#define NCUTS 500000
#define NT 125                       // 64-bin tiles per region
#define NKL (NROI * NT + NROI)       // 32256 KL partial slots

__global__ void k_init(const float* __restrict__ comp,
                       float* __restrict__ g2, float* __restrict__ compT)
{
    const int tid = threadIdx.x;
    for (int i = tid; i < 400; i += 256) {
        const int a = i / 20, b = i % 20;
        float s = 0.f;
#pragma unroll
        for (int c = 0; c < 20; c++) s += comp[a * 20 + c] * comp[b * 20 + c];
        // upper-triangular, off-diag doubled: q = sum_a x_a * sum_{b>=a} g2 x_b
        g2[i] = (b < a) ? 0.f : (b == a ? s : 2.f * s);
        compT[i] = comp[b * 20 + a];   // compT[c*20+a] = comp[a*20+c]
    }
}

// q += x^T G x, G via uniform s_loads (triangular, off-diag doubled)
#define QUAD(x)                                             \
    do {                                                    \
        _Pragma("unroll")                                   \
        for (int a_ = 0; a_ < 20; a_++) {                   \
            float t_ = g2[a_ * 21] * x[a_];                 \
            _Pragma("unroll")                               \
            for (int b_ = a_ + 1; b_ < 20; b_++)            \
                t_ += g2[a_ * 20 + b_] * x[b_];             \
            q += x[a_] * t_;                                \
        }                                                   \
    } while (0)

__global__ __launch_bounds__(64, 6) void k_main(
    const float* __restrict__ g2, const float* __restrict__ compT,
    const float* __restrict__ wb0, const float* __restrict__ wd0,
    const float* __restrict__ wb1, const float* __restrict__ wd1,
    const float* __restrict__ wb2, const float* __restrict__ wd2,
    const float* __restrict__ wb3, const float* __restrict__ wd3,
    const float* __restrict__ wb4, const float* __restrict__ wd4,
    const float* __restrict__ wb5, const float* __restrict__ wd5,
    const float* __restrict__ wb6, const float* __restrict__ wd6,
    const int* __restrict__ regions_oi,
    __hip_bfloat16* __restrict__ w2,
    float* __restrict__ s_part, float* __restrict__ klbuf)
{
    __shared__ float U_sh[20 * 64];    // 5120 B
    __shared__ float cs_sh[20 * 16];   // 1280 B
    __shared__ float biasf[64];        // 256 B  => 6656 B total

    const int lane = threadIdx.x;
    const int t = blockIdx.x;          // 0..124
    const int r = blockIdx.y;          // 0..255
    const int base = t * 64;
    const int j = base + lane;
    const int r0 = regions_oi[r];

    const float* __restrict__ p6 = wd6 + (size_t)r0 * (20 * 8000);
    const float* __restrict__ p5 = wd5 + (size_t)r0 * (20 * 4000);
    const float* __restrict__ p4 = wd4 + (size_t)r0 * (20 * 2000);
    const float* __restrict__ p3 = wd3 + (size_t)r0 * (20 * 1000);
    const float* __restrict__ p2 = wd2 + (size_t)r0 * (20 * 400);
    const float* __restrict__ p1 = wd1 + (size_t)r0 * (20 * 200);
    const float* __restrict__ p0 = wd0 + (size_t)r0 * (20 * 40);
    const float* __restrict__ b6 = wb6 + (size_t)r0 * 8000;
    const float* __restrict__ b5 = wb5 + (size_t)r0 * 4000;
    const float* __restrict__ b4 = wb4 + (size_t)r0 * 2000;
    const float* __restrict__ b3 = wb3 + (size_t)r0 * 1000;
    const float* __restrict__ b2 = wb2 + (size_t)r0 * 400;
    const float* __restrict__ b1 = wb1 + (size_t)r0 * 200;
    const float* __restrict__ b0 = wb0 + (size_t)r0 * 40;

    // ---- cs: 320 (a,quad) units = 5 x 64 lanes ----
#pragma unroll
    for (int k = 0; k < 5; k++) {
        const int u = lane + (k << 6);
        const int a = u >> 4, qd = u & 15;
        const int jq = base + 4 * qd;
        cs_sh[a * 16 + qd] = p4[a * 2000 + (jq >> 2)] + p3[a * 1000 + (jq >> 3)]
                           + p2[a * 400 + jq / 20] + p1[a * 200 + jq / 40]
                           + p0[a * 40 + jq / 200];
    }
    // ---- bias per bin ----
    biasf[lane] = b6[j] + b5[j >> 1] + b4[j >> 2] + b3[j >> 3]
                + b2[j / 20] + b1[j / 40] + b0[j / 200];

    // ---- L6 into registers (lane = bin column) + KL quad ----
    float x[20];
#pragma unroll
    for (int a = 0; a < 20; a++) x[a] = p6[(size_t)a * 8000 + j];
    float q = 0.f;
    QUAD(x);

    // ---- U = x6 + x5 + cs -> LDS (wave-synchronous; no barrier) ----
#pragma unroll
    for (int a = 0; a < 20; a++)
        U_sh[a * 64 + lane] = x[a] + p5[a * 4000 + (base >> 1) + (lane >> 1)]
                            + cs_sh[a * 16 + (lane >> 2)];

    // ---- KL quads for L5/L4/L3: one column-unit per lane ----
    {
        const float* P = nullptr; int K = 0, col = 0;
        if (lane < 32)      { P = p5; K = 4000; col = (base >> 1) + lane; }
        else if (lane < 48) { P = p4; K = 2000; col = (base >> 2) + lane - 32; }
        else if (lane < 56) { P = p3; K = 1000; col = (base >> 3) + lane - 48; }
        if (P) {
            float y[20];
#pragma unroll
            for (int a = 0; a < 20; a++) y[a] = P[(size_t)a * K + col];
#pragma unroll
            for (int a_ = 0; a_ < 20; a_++) {
                float t_ = g2[a_ * 21] * y[a_];
#pragma unroll
                for (int b_ = a_ + 1; b_ < 20; b_++) t_ += g2[a_ * 20 + b_] * y[b_];
                q += y[a_] * t_;
            }
        }
    }
#pragma unroll
    for (int off = 32; off > 0; off >>= 1) q += __shfl_down(q, off, 64);
    if (lane == 0) klbuf[(size_t)r * NT + t] = q;

    // ---- w-projection: 5 passes x 4 clusters (compT via uniform s_load) ----
    const float bi = biasf[lane];
    __hip_bfloat16* wp = w2 + (size_t)r * 20 * 8000 + j;
    float* spp = s_part + ((size_t)r * NT + t) * 20;
#pragma unroll 1
    for (int p = 0; p < 5; p++) {
        const int c0 = p * 4;
        const float* __restrict__ cc = compT + c0 * 20;
        float a0 = bi, a1 = bi, a2 = bi, a3 = bi;
#pragma unroll
        for (int a = 0; a < 20; a++) {
            const float u = U_sh[a * 64 + lane];
            a0 += cc[a] * u;
            a1 += cc[20 + a] * u;
            a2 += cc[40 + a] * u;
            a3 += cc[60 + a] * u;
        }
        wp[(size_t)(c0 + 0) * 8000] = __float2bfloat16(a0);
        wp[(size_t)(c0 + 1) * 8000] = __float2bfloat16(a1);
        wp[(size_t)(c0 + 2) * 8000] = __float2bfloat16(a2);
        wp[(size_t)(c0 + 3) * 8000] = __float2bfloat16(a3);
        // |w| small (~<4): unnormalized exp-sum safe in f32
        float s0 = __expf(a0), s1 = __expf(a1), s2 = __expf(a2), s3 = __expf(a3);
#pragma unroll
        for (int off = 32; off > 0; off >>= 1) {
            s0 += __shfl_down(s0, off, 64);
            s1 += __shfl_down(s1, off, 64);
            s2 += __shfl_down(s2, off, 64);
            s3 += __shfl_down(s3, off, 64);
        }
        if (lane == 0) {
            spp[c0 + 0] = s0; spp[c0 + 1] = s1;
            spp[c0 + 2] = s2; spp[c0 + 3] = s3;
        }
    }
}

// KL quads for levels 0..2 (40+200+400 = 640 cols per region)
__global__ __launch_bounds__(256, 2) void k_klc(
    const float* __restrict__ g2,
    const float* __restrict__ wd0, const float* __restrict__ wd1,
    const float* __restrict__ wd2,
    const int* __restrict__ regions_oi, float* __restrict__ klbuf)
{
    __shared__ float klp[4];
    const int tid = threadIdx.x;
    const int r0 = regions_oi[blockIdx.x];
    const float* __restrict__ p2 = wd2 + (size_t)r0 * (20 * 400);
    const float* __restrict__ p1 = wd1 + (size_t)r0 * (20 * 200);
    const float* __restrict__ p0 = wd0 + (size_t)r0 * (20 * 40);

    float q = 0.f;
#pragma unroll 1
    for (int it = 0; it < 3; it++) {
        const int u = it * 256 + tid;
        if (u >= 640) break;
        const float* P; int K, col;
        if (u < 400)      { P = p2; K = 400; col = u; }
        else if (u < 600) { P = p1; K = 200; col = u - 400; }
        else              { P = p0; K = 40;  col = u - 600; }
        float x[20];
#pragma unroll
        for (int a = 0; a < 20; a++) x[a] = P[a * K + col];
#pragma unroll
        for (int a_ = 0; a_ < 20; a_++) {
            float t_ = g2[a_ * 21] * x[a_];
#pragma unroll
            for (int b_ = a_ + 1; b_ < 20; b_++) t_ += g2[a_ * 20 + b_] * x[b_];
            q += x[a_] * t_;
        }
    }
#pragma unroll
    for (int off = 32; off > 0; off >>= 1) q += __shfl_down(q, off, 64);
    if ((tid & 63) == 0) klp[tid >> 6] = q;
    __syncthreads();
    if (tid == 0)
        klbuf[(size_t)NROI * NT + blockIdx.x] = klp[0] + klp[1] + klp[2] + klp[3];
}

// final KL reduction: 32256 partials -> kl scalar (closed-form const folded)
__global__ void k_klred(const float* __restrict__ klbuf, float* __restrict__ kl)
{
    __shared__ float part[4];
    const int tid = threadIdx.x;
    float s = 0.f;
    for (int i = tid; i < NKL; i += 256) s += klbuf[i];
#pragma unroll
    for (int off = 32; off > 0; off >>= 1) s += __shfl_down(s, off, 64);
    if ((tid & 63) == 0) part[tid >> 6] = s;
    __syncthreads();
    if (tid == 0)
        kl[0] = (float)(-80076800.0 * 1.3244036413128371)
              + (part[0] + part[1] + part[2] + part[3]) * (-0.5f / 2.25f);
}

__global__ void k_sub(const float* __restrict__ s_part, float* __restrict__ sub)
{
    const int i = blockIdx.x * 256 + threadIdx.x;
    if (i >= NROI * NC) return;
    const int r = i / 20, c = i % 20;
    float s = 0.f;
#pragma unroll 1
    for (int t = 0; t < NT; t++) s += s_part[((size_t)r * NT + t) * 20 + c];
    sub[i] = logf(s) + 3.2188758248682006f;   // + log(25)
}

__global__ void k_gather(const int* __restrict__ lri, const int* __restrict__ lci,
                         const int* __restrict__ cli, const int* __restrict__ coords,
                         const __hip_bfloat16* __restrict__ w2,
                         const float* __restrict__ sub,
                         float* __restrict__ out)
{
    const int i = blockIdx.x * 256 + threadIdx.x;
    if (i >= NCUTS) return;
    const int r = lri[i];
    const int c = cli[lci[i]];
    int co = coords[i];
    co = co < 0 ? 0 : (co > 199999 ? 199999 : co);
    const int bin = co / 25;
    const int rc = r * 20 + c;
    out[i] = __bfloat162float(w2[(size_t)rc * 8000 + bin]) - sub[rc];
}

extern "C" void kernel_launch(void* const* d_in, const int* in_sizes, int n_in,
                              void* d_out, int out_size, void* d_ws, size_t ws_size,
                              hipStream_t stream)
{
    const float* comp = (const float*)d_in[0];
    const float* wb[7];
    const float* wd[7];
    if (in_sizes[2] == 400000) {
        for (int l = 0; l < 7; l++) { wb[l] = (const float*)d_in[1 + 2 * l]; wd[l] = (const float*)d_in[2 + 2 * l]; }
    } else {
        for (int l = 0; l < 7; l++) { wb[l] = (const float*)d_in[1 + l]; wd[l] = (const float*)d_in[8 + l]; }
    }
    const int* regions_oi = (const int*)d_in[15];
    const int* lri   = (const int*)d_in[16];
    const int* lci   = (const int*)d_in[17];
    const int* cli   = (const int*)d_in[18];
    const int* coords= (const int*)d_in[19];
    float* out = (float*)d_out;

    __hip_bfloat16* w2 = (__hip_bfloat16*)d_ws;                     // 81.92 MB
    float* s_part = (float*)(w2 + (size_t)NROI * NC * NFINAL);      // 32000*20 f32
    float* sub    = s_part + (size_t)NROI * NT * 20;                // 5120 f32
    float* g2buf  = sub + NROI * NC;                                // 400 f32
    float* compT  = g2buf + 400;                                    // 400 f32
    float* klbuf  = compT + 400;                                    // 32256 f32
    const size_t need = (size_t)NROI * NC * NFINAL * 2
                      + ((size_t)NROI * NT * 20 + NROI * NC + 800 + NKL)
                        * sizeof(float);
    if (ws_size < need) return;

    k_init<<<1, 256, 0, stream>>>(comp, g2buf, compT);
    k_main<<<dim3(NT, NROI), 64, 0, stream>>>(g2buf, compT,
        wb[0], wd[0], wb[1], wd[1], wb[2], wd[2], wb[3], wd[3],
        wb[4], wd[4], wb[5], wd[5], wb[6], wd[6],
        regions_oi, w2, s_part, klbuf);
    k_klc<<<NROI, 256, 0, stream>>>(g2buf, wd[0], wd[1], wd[2],
        regions_oi, klbuf);
    k_klred<<<1, 256, 0, stream>>>(klbuf, out + NCUTS);
    k_sub<<<(NROI * NC + 255) / 256, 256, 0, stream>>>(s_part, sub);
    k_gather<<<(NCUTS + 255) / 256, 256, 0, stream>>>(lri, lci, cli, coords,
        w2, sub, out);
}

// Round 20
// 225.029 us; speedup vs baseline: 1.0364x; 1.0364x over previous
//
#include <hip/hip_runtime.h>
#include <hip/hip_bf16.h>
#include <math.h>

// SharedLora on MI355X — round 20: homogeneous split kernels, no w2.
// 19 rounds: every FUSED k_main = 185-215us regardless of structure, while
// r16 ablation gives stage=65 (HBM roofline) + rest=130 that won't overlap.
// Harness fill proves homogeneous streams hit 7 TB/s. r20:
//   k_stage: C+U+M1(syrk) -> writes U bin-major bf16 (82MB) + bias f32 (8MB).
//            No exp/shuffles/M2. LDS 5KB.
//   k_sexp : reads U/bias (L2/L3-hot), fB frags DIRECT from global (no LDS),
//            r12-validated MFMA proj + exp + 4-step shuffle reduce -> s_part.
//   k_gather: on-demand w = bias + compT.U-row (40B L3-hot row per cut);
//            w2 never materialized.

#define NROI 256
#define NC 20
#define NFINAL 8000
#define NCUTS 500000
#define TB 256
#define NTILE 32
#define NKL (NROI * NTILE + NROI)

typedef __attribute__((ext_vector_type(8))) short bf16x8;
typedef __attribute__((ext_vector_type(4))) float f32x4;

static __device__ __forceinline__ ushort bfr(float x) {
    union { __hip_bfloat16 h; ushort u; } v;
    v.h = __float2bfloat16(x);
    return v.u;
}
static __device__ __forceinline__ float b2f(ushort u) {
    union { float f; unsigned x; } v;
    v.x = ((unsigned)u) << 16;
    return v.f;
}
static __device__ __forceinline__ bf16x8 pack8(float4 a, float4 b) {
    union { bf16x8 v; ushort s[8]; } u;
    u.s[0] = bfr(a.x); u.s[1] = bfr(a.y); u.s[2] = bfr(a.z); u.s[3] = bfr(a.w);
    u.s[4] = bfr(b.x); u.s[5] = bfr(b.y); u.s[6] = bfr(b.z); u.s[7] = bfr(b.w);
    return u.v;
}

__global__ void k_init(const float* __restrict__ comp,
                       float* __restrict__ g2, float* __restrict__ gfull,
                       float* __restrict__ compT, ushort* __restrict__ compPad)
{
    const int tid = threadIdx.x;
    for (int i = tid; i < 400; i += 256) {
        const int a = i / 20, b = i % 20;
        float s = 0.f;
#pragma unroll
        for (int c = 0; c < 20; c++) s += comp[a * 20 + c] * comp[b * 20 + c];
        g2[i] = (b < a) ? 0.f : (b == a ? s : 2.f * s);   // triangular (k_klc)
        compT[i] = comp[b * 20 + a];                      // compT[c][a] f32
    }
    for (int i = tid; i < 1024; i += 256) {
        const int rr = i >> 5, cc = i & 31;
        float s = 0.f;
        if (rr < 20 && cc < 20) {
#pragma unroll
            for (int c = 0; c < 20; c++) s += comp[rr * 20 + c] * comp[cc * 20 + c];
        }
        gfull[i] = s;
        const float v = (rr < 20 && cc < 20) ? comp[cc * 20 + rr] : 0.f;
        compPad[i] = bfr(v);                              // compPad[cluster][a]
    }
}

// ---- k_stage: levels -> U (bin-major bf16) + bias (f32) + KL syrk ----
__global__ __launch_bounds__(256, 2) void k_stage(
    const float* __restrict__ gfull,
    const float* __restrict__ wb0, const float* __restrict__ wd0,
    const float* __restrict__ wb1, const float* __restrict__ wd1,
    const float* __restrict__ wb2, const float* __restrict__ wd2,
    const float* __restrict__ wb3, const float* __restrict__ wd3,
    const float* __restrict__ wb4, const float* __restrict__ wd4,
    const float* __restrict__ wb5, const float* __restrict__ wd5,
    const float* __restrict__ wb6, const float* __restrict__ wd6,
    const int* __restrict__ regions_oi,
    ushort* __restrict__ Ubuf, float* __restrict__ biasG,
    float* __restrict__ klbuf)
{
    __shared__ float cs_sh[20 * 64];   // 5 KiB
    __shared__ float klp[4];

    const int tid = threadIdx.x;
    const int wv = tid >> 6, ln = tid & 63;
    const int l15 = ln & 15, lg = ln >> 4;
    const int r = blockIdx.x >> 5;
    const int tile = blockIdx.x & 31;
    const int base = tile << 8;
    const int r0 = regions_oi[r];

    const float* __restrict__ p6 = wd6 + (size_t)r0 * (20 * 8000);
    const float* __restrict__ p5 = wd5 + (size_t)r0 * (20 * 4000);
    const float* __restrict__ p4 = wd4 + (size_t)r0 * (20 * 2000);
    const float* __restrict__ p3 = wd3 + (size_t)r0 * (20 * 1000);
    const float* __restrict__ p2 = wd2 + (size_t)r0 * (20 * 400);
    const float* __restrict__ p1 = wd1 + (size_t)r0 * (20 * 200);
    const float* __restrict__ p0 = wd0 + (size_t)r0 * (20 * 40);
    const float* __restrict__ b6 = wb6 + (size_t)r0 * 8000;
    const float* __restrict__ b5 = wb5 + (size_t)r0 * 4000;
    const float* __restrict__ b4 = wb4 + (size_t)r0 * 2000;
    const float* __restrict__ b3 = wb3 + (size_t)r0 * 1000;
    const float* __restrict__ b2 = wb2 + (size_t)r0 * 400;
    const float* __restrict__ b1 = wb1 + (size_t)r0 * 200;
    const float* __restrict__ b0 = wb0 + (size_t)r0 * 40;

    // ---- C: coarse sums (L4..L0) into cs_sh ----
#pragma unroll
    for (int it = 0; it < 5; it++) {
        const int u = it * 256 + tid;
        const int a = u >> 6, qd = u & 63;
        const int j = base + 4 * qd;
        float v = 0.f;
        if (j < NFINAL)
            v = p4[a * 2000 + (j >> 2)] + p3[a * 1000 + (j >> 3)]
              + p2[a * 400 + j / 20] + p1[a * 200 + j / 40]
              + p0[a * 40 + j / 200];
        cs_sh[a * 64 + qd] = v;
    }
    // ---- bias -> biasG (register-only path) ----
    {
        const int j = base + tid;
        if (j < NFINAL)
            biasG[(size_t)r * 8000 + j] =
                b6[j] + b5[j >> 1] + b4[j >> 2] + b3[j >> 3]
              + b2[j / 20] + b1[j / 40] + b0[j / 200];
    }
    __syncthreads();

    // ---- U: thread = bin; 5 a-quads -> ushort4 stores, bin-major ----
    {
        const int j = base + tid;
        const bool ok = j < NFINAL;
        const int qd = tid >> 2;
        ushort* urow = Ubuf + (size_t)(r * 8000 + (ok ? j : 0)) * 20;
#pragma unroll
        for (int it = 0; it < 5; it++) {
            float u[4];
#pragma unroll
            for (int i = 0; i < 4; i++) {
                const int a = 4 * it + i;
                float x6 = 0.f, x5 = 0.f;
                if (ok) {
                    x6 = p6[(size_t)a * 8000 + j];
                    x5 = p5[a * 4000 + (j >> 1)];
                }
                u[i] = x6 + x5 + cs_sh[a * 64 + qd];
            }
            if (ok)
                *(ushort4*)(urow + 4 * it) =
                    make_ushort4(bfr(u[0]), bfr(u[1]), bfr(u[2]), bfr(u[3]));
        }
    }

    // ---- M1: KL syrk (fragments direct from global, L1/L2-hot) ----
    {
        f32x4 s00 = {0.f, 0.f, 0.f, 0.f};
        f32x4 s10 = {0.f, 0.f, 0.f, 0.f};
        f32x4 s11 = {0.f, 0.f, 0.f, 0.f};
#pragma unroll
        for (int i = 0; i < 4; i++) {
            const int ch = wv + 4 * i;
            if (ch < 15) {
                const float* P; int K, col0;
                if (ch < 8)       { P = p6; K = 8000; col0 = base + ch * 32; }
                else if (ch < 12) { P = p5; K = 4000; col0 = (base >> 1) + (ch - 8) * 32; }
                else if (ch < 14) { P = p4; K = 2000; col0 = (base >> 2) + (ch - 12) * 32; }
                else              { P = p3; K = 1000; col0 = (base >> 3); }
                const int cb = col0 + lg * 8;
                bf16x8 flo = {0,0,0,0,0,0,0,0}, fhi = {0,0,0,0,0,0,0,0};
                if (cb < K) {   // cb, K multiples of 8 -> all-or-nothing
                    const float4 xa = *(const float4*)(P + (size_t)l15 * K + cb);
                    const float4 xb = *(const float4*)(P + (size_t)l15 * K + cb + 4);
                    flo = pack8(xa, xb);
                    if (l15 < 4) {
                        const float4 ya = *(const float4*)(P + (size_t)(16 + l15) * K + cb);
                        const float4 yb = *(const float4*)(P + (size_t)(16 + l15) * K + cb + 4);
                        fhi = pack8(ya, yb);
                    }
                }
                s00 = __builtin_amdgcn_mfma_f32_16x16x32_bf16(flo, flo, s00, 0, 0, 0);
                s10 = __builtin_amdgcn_mfma_f32_16x16x32_bf16(fhi, flo, s10, 0, 0, 0);
                s11 = __builtin_amdgcn_mfma_f32_16x16x32_bf16(fhi, fhi, s11, 0, 0, 0);
            }
        }
        float qp = 0.f;
#pragma unroll
        for (int reg = 0; reg < 4; reg++) {
            const int rlo = lg * 4 + reg, rhi = 16 + lg * 4 + reg;
            qp += gfull[rlo * 32 + l15] * s00[reg];
            qp += 2.f * gfull[rhi * 32 + l15] * s10[reg];
            qp += gfull[rhi * 32 + 16 + l15] * s11[reg];
        }
#pragma unroll
        for (int off = 32; off > 0; off >>= 1) qp += __shfl_down(qp, off, 64);
        if (ln == 0) klp[wv] = qp;
    }
    __syncthreads();
    if (tid == 0) klbuf[blockIdx.x] = klp[0] + klp[1] + klp[2] + klp[3];
}

// ---- k_sexp: U(L3-hot) -> MFMA proj -> exp -> per-wave s_part ----
__global__ __launch_bounds__(256, 2) void k_sexp(
    const ushort* __restrict__ compPad,
    const ushort* __restrict__ Ubuf, const float* __restrict__ biasG,
    float* __restrict__ s_part)
{
    const int tid = threadIdx.x;
    const int wv = tid >> 6, ln = tid & 63;
    const int l15 = ln & 15, lg = ln >> 4;
    const int r = blockIdx.x >> 5;
    const int tile = blockIdx.x & 31;
    const int base = tile << 8;

    bf16x8 fA0 = *(const bf16x8*)&compPad[l15 * 32 + lg * 8];        // c 0-15
    bf16x8 fA1 = *(const bf16x8*)&compPad[(16 + l15) * 32 + lg * 8]; // c 16-19

    float sA[4] = {0.f, 0.f, 0.f, 0.f};
    float sB[4] = {0.f, 0.f, 0.f, 0.f};
#pragma unroll
    for (int t = 0; t < 4; t++) {
        const int nt = 4 * t + wv;
        const int bin = base + nt * 16 + l15;
        const bool ok = bin < NFINAL;
        bf16x8 fb = {0, 0, 0, 0, 0, 0, 0, 0};
        float bi = 0.f;
        if (ok) {
            const ushort* row = Ubuf + (size_t)(r * 8000 + bin) * 20;
            union { bf16x8 v; ushort4 q[2]; } u;
            u.q[0] = make_ushort4(0, 0, 0, 0);
            u.q[1] = make_ushort4(0, 0, 0, 0);
            if (lg < 2) {
                u.q[0] = *(const ushort4*)(row + lg * 8);
                u.q[1] = *(const ushort4*)(row + lg * 8 + 4);
            } else if (lg == 2) {
                u.q[0] = *(const ushort4*)(row + 16);
            }
            fb = u.v;
            bi = biasG[(size_t)r * 8000 + bin];
        }
        const f32x4 z = {0.f, 0.f, 0.f, 0.f};
        f32x4 c0 = __builtin_amdgcn_mfma_f32_16x16x32_bf16(fA0, fb, z, 0, 0, 0);
        f32x4 c1 = __builtin_amdgcn_mfma_f32_16x16x32_bf16(fA1, fb, z, 0, 0, 0);
        if (ok) {
#pragma unroll
            for (int reg = 0; reg < 4; reg++) {
                // |w| small (~<4): unnormalized exp-sum safe in f32
                sA[reg] += __expf(bi + c0[reg]);
                if (lg == 0) sB[reg] += __expf(bi + c1[reg]);
            }
        }
    }
    float* spp = s_part + ((size_t)blockIdx.x * 4 + wv) * 20;
#pragma unroll
    for (int reg = 0; reg < 4; reg++) {
        float s = sA[reg];
        s += __shfl_xor(s, 1, 64); s += __shfl_xor(s, 2, 64);
        s += __shfl_xor(s, 4, 64); s += __shfl_xor(s, 8, 64);
        if (l15 == 0) spp[lg * 4 + reg] = s;   // cluster lg*4+reg
        float sb = sB[reg];
        sb += __shfl_xor(sb, 1, 64); sb += __shfl_xor(sb, 2, 64);
        sb += __shfl_xor(sb, 4, 64); sb += __shfl_xor(sb, 8, 64);
        sb += __shfl_xor(sb, 16, 64); sb += __shfl_xor(sb, 32, 64);
        if (ln == 0) spp[16 + reg] = sb;       // clusters 16-19
    }
}

// KL quads for levels 0..2 (40+200+400 = 640 cols per region)
__global__ __launch_bounds__(256, 2) void k_klc(
    const float* __restrict__ g2,
    const float* __restrict__ wd0, const float* __restrict__ wd1,
    const float* __restrict__ wd2,
    const int* __restrict__ regions_oi, float* __restrict__ klbuf)
{
    __shared__ float klp[4];
    const int tid = threadIdx.x;
    const int r0 = regions_oi[blockIdx.x];
    const float* __restrict__ p2 = wd2 + (size_t)r0 * (20 * 400);
    const float* __restrict__ p1 = wd1 + (size_t)r0 * (20 * 200);
    const float* __restrict__ p0 = wd0 + (size_t)r0 * (20 * 40);

    float q = 0.f;
#pragma unroll 1
    for (int it = 0; it < 3; it++) {
        const int u = it * 256 + tid;
        if (u >= 640) break;
        const float* P; int K, col;
        if (u < 400)      { P = p2; K = 400; col = u; }
        else if (u < 600) { P = p1; K = 200; col = u - 400; }
        else              { P = p0; K = 40;  col = u - 600; }
        float x[20];
#pragma unroll
        for (int a = 0; a < 20; a++) x[a] = P[a * K + col];
#pragma unroll
        for (int a_ = 0; a_ < 20; a_++) {
            float t_ = g2[a_ * 21] * x[a_];
#pragma unroll
            for (int b_ = a_ + 1; b_ < 20; b_++) t_ += g2[a_ * 20 + b_] * x[b_];
            q += x[a_] * t_;
        }
    }
#pragma unroll
    for (int off = 32; off > 0; off >>= 1) q += __shfl_down(q, off, 64);
    if ((tid & 63) == 0) klp[tid >> 6] = q;
    __syncthreads();
    if (tid == 0)
        klbuf[NROI * NTILE + blockIdx.x] = klp[0] + klp[1] + klp[2] + klp[3];
}

__global__ void k_klred(const float* __restrict__ klbuf, float* __restrict__ kl)
{
    __shared__ float part[4];
    const int tid = threadIdx.x;
    float s = 0.f;
    for (int i = tid; i < NKL; i += 256) s += klbuf[i];
#pragma unroll
    for (int off = 32; off > 0; off >>= 1) s += __shfl_down(s, off, 64);
    if ((tid & 63) == 0) part[tid >> 6] = s;
    __syncthreads();
    if (tid == 0)
        kl[0] = (float)(-80076800.0 * 1.3244036413128371)
              + (part[0] + part[1] + part[2] + part[3]) * (-0.5f / 2.25f);
}

__global__ void k_sub(const float* __restrict__ s_part, float* __restrict__ sub)
{
    const int i = blockIdx.x * 256 + threadIdx.x;
    if (i >= NROI * NC) return;
    const int r = i / 20, c = i % 20;
    float s = 0.f;
#pragma unroll 1
    for (int t = 0; t < NTILE * 4; t++)
        s += s_part[((size_t)r * NTILE * 4 + t) * 20 + c];
    sub[i] = logf(s) + 3.2188758248682006f;   // + log(25)
}

// on-demand w: bias + compT[c] . U-row (40B, L3-hot); no w2 array
__global__ void k_gather(const int* __restrict__ lri, const int* __restrict__ lci,
                         const int* __restrict__ cli, const int* __restrict__ coords,
                         const ushort* __restrict__ Ubuf,
                         const float* __restrict__ biasG,
                         const float* __restrict__ compT,
                         const float* __restrict__ sub,
                         float* __restrict__ out)
{
    const int i = blockIdx.x * 256 + threadIdx.x;
    if (i >= NCUTS) return;
    const int r = lri[i];
    const int c = cli[lci[i]];
    int co = coords[i];
    co = co < 0 ? 0 : (co > 199999 ? 199999 : co);
    const int bin = co / 25;
    const ushort* row = Ubuf + (size_t)(r * 8000 + bin) * 20;
    const float* cc = compT + c * 20;
    float w = biasG[(size_t)r * 8000 + bin];
#pragma unroll
    for (int k = 0; k < 5; k++) {
        const ushort4 u4 = *(const ushort4*)(row + 4 * k);
        w += cc[4 * k + 0] * b2f(u4.x) + cc[4 * k + 1] * b2f(u4.y)
           + cc[4 * k + 2] * b2f(u4.z) + cc[4 * k + 3] * b2f(u4.w);
    }
    out[i] = w - sub[r * 20 + c];
}

extern "C" void kernel_launch(void* const* d_in, const int* in_sizes, int n_in,
                              void* d_out, int out_size, void* d_ws, size_t ws_size,
                              hipStream_t stream)
{
    const float* comp = (const float*)d_in[0];
    const float* wb[7];
    const float* wd[7];
    if (in_sizes[2] == 400000) {
        for (int l = 0; l < 7; l++) { wb[l] = (const float*)d_in[1 + 2 * l]; wd[l] = (const float*)d_in[2 + 2 * l]; }
    } else {
        for (int l = 0; l < 7; l++) { wb[l] = (const float*)d_in[1 + l]; wd[l] = (const float*)d_in[8 + l]; }
    }
    const int* regions_oi = (const int*)d_in[15];
    const int* lri   = (const int*)d_in[16];
    const int* lci   = (const int*)d_in[17];
    const int* cli   = (const int*)d_in[18];
    const int* coords= (const int*)d_in[19];
    float* out = (float*)d_out;

    ushort* Ubuf  = (ushort*)d_ws;                          // 41M bf16 = 82MB
    float* biasG  = (float*)(Ubuf + (size_t)NROI * NFINAL * 20);  // 8MB
    float* s_part = biasG + (size_t)NROI * NFINAL;          // 8192*4*20 f32
    float* sub    = s_part + (size_t)NROI * NTILE * 4 * 20; // 5120 f32
    float* g2buf  = sub + NROI * NC;                        // 400
    float* gfull  = g2buf + 400;                            // 1024
    float* compT  = gfull + 1024;                           // 400
    ushort* compPad = (ushort*)(compT + 400);               // 1024 u16
    float* klbuf  = (float*)(compPad + 1024);               // 8448
    const size_t need = (size_t)NROI * NFINAL * 20 * 2
                      + ((size_t)NROI * NFINAL + NROI * NTILE * 4 * 20
                         + NROI * NC + 400 + 1024 + 400 + 512 + NKL)
                        * sizeof(float);
    if (ws_size < need) return;

    k_init<<<1, 256, 0, stream>>>(comp, g2buf, gfull, compT, compPad);
    k_stage<<<NROI * NTILE, 256, 0, stream>>>(gfull,
        wb[0], wd[0], wb[1], wd[1], wb[2], wd[2], wb[3], wd[3],
        wb[4], wd[4], wb[5], wd[5], wb[6], wd[6],
        regions_oi, Ubuf, biasG, klbuf);
    k_sexp<<<NROI * NTILE, 256, 0, stream>>>(compPad, Ubuf, biasG, s_part);
    k_klc<<<NROI, 256, 0, stream>>>(g2buf, wd[0], wd[1], wd[2],
        regions_oi, klbuf);
    k_klred<<<1, 256, 0, stream>>>(klbuf, out + NCUTS);
    k_sub<<<(NROI * NC + 255) / 256, 256, 0, stream>>>(s_part, sub);
    k_gather<<<(NCUTS + 255) / 256, 256, 0, stream>>>(lri, lci, cli, coords,
        Ubuf, biasG, compT, sub, out);
}